// Round 3
// baseline (107.972 us; speedup 1.0000x reference)
//
#include <hip/hip_runtime.h>
#include <stdint.h>
#include <math.h>

// Negative L1 cdist: out[n,m] = -sum_d |x[n,d] - w[m,d]|
// N=8192, M=1024, D=64, fp32 in/out.
//
// R10 post-mortem: un-spilled f16 path (96 VOP3P ops/output) ran ~37us --
// SLOWER than R8's u8-sad (~27us). Packed-f16/fdot2 is ~7-8 cyc/op on
// gfx950 (sub-rate or fallback-emitted). Lesson: only trust measured-rate
// instructions. The sole HW-verified full-rate op is scalar f32 VALU
// (m07: 2 cyc/wave-op).
// R11: pure-f32 path, 2 full-rate ops/elem (v_sub_f32 + v_add_f32 with
// free |.| input modifier) = 128 ops/output -> 13.7us VALU floor.
//   - NO LDS (per-CU LDS port would bottleneck at 1 col/lane); x rows are
//     block-uniform -> uniform loads promote to s_load / SGPR broadcast
//     (free scalar operand in v_sub_f32).
//   - w row in 64 VGPRs, 1 m-col/lane, ~85 VGPR total (128 budget, no spill).
//   - cvt/quant kernel DELETED; no workspace; absmax ~1e-3 (f32-exact).
// Grid: NR=16 rows/block -> 2048 blocks = 8/CU for TLP; 4 indep acc chains
// hide v_add latency; nontemporal stores keep w L2-resident.

constexpr int Nn = 8192, Mm = 1024, Dd = 64;
constexpr int NR = 16;                        // n-rows per block

__global__ __launch_bounds__(256, 4) void cdist_l1_f32_kernel(
    const float* __restrict__ x, const float* __restrict__ w,
    float* __restrict__ out)
{
    const int t   = threadIdx.x;
    const int bid = blockIdx.x;
    const int mg  = bid & 3;                  // m-group: 256 columns each
    const int n0  = (bid >> 2) * NR;
    const int m   = mg * 256 + t;

    // per-lane w row: 64 f32 VGPRs, loaded once (w is 256 KB, L2-hot)
    float wr[Dd];
    {
        const float4* wp = (const float4*)(w + (size_t)m * Dd);
#pragma unroll
        for (int i = 0; i < Dd / 4; ++i) {
            const float4 v = wp[i];
            wr[4 * i + 0] = v.x; wr[4 * i + 1] = v.y;
            wr[4 * i + 2] = v.z; wr[4 * i + 3] = v.w;
        }
    }

    float* o = out + (size_t)n0 * Mm + m;
    for (int r = 0; r < NR; ++r) {
        // block-uniform address -> compiler promotes to s_load (SGPR broadcast)
        const float* __restrict__ xr = x + (size_t)(n0 + r) * Dd;
        float a0 = 0.f, a1 = 0.f, a2 = 0.f, a3 = 0.f;
#pragma unroll
        for (int k = 0; k < Dd; k += 4) {
            // v_sub_f32 + v_add_f32(acc, acc, abs(d)) -- 2 full-rate ops/elem
            a0 += __builtin_fabsf(xr[k + 0] - wr[k + 0]);
            a1 += __builtin_fabsf(xr[k + 1] - wr[k + 1]);
            a2 += __builtin_fabsf(xr[k + 2] - wr[k + 2]);
            a3 += __builtin_fabsf(xr[k + 3] - wr[k + 3]);
        }
        // coalesced (256 B/wave); nontemporal: don't thrash L2 (keep w hot)
        __builtin_nontemporal_store(-((a0 + a1) + (a2 + a3)),
                                    o + (size_t)r * Mm);
    }
}

extern "C" void kernel_launch(void* const* d_in, const int* in_sizes, int n_in,
                              void* d_out, int out_size, void* d_ws, size_t ws_size,
                              hipStream_t stream) {
    (void)in_sizes; (void)n_in; (void)out_size; (void)d_ws; (void)ws_size;
    const float* x = (const float*)d_in[0];   // [8192, 64] fp32
    const float* w = (const float*)d_in[1];   // [1024, 64] fp32
    float* out = (float*)d_out;               // [8192, 1024] fp32

    // (8192/16) n-blocks x 4 m-groups = 2048 blocks = 8 blocks/CU
    cdist_l1_f32_kernel<<<dim3((Nn / NR) * 4), dim3(256), 0, stream>>>(
        x, w, out);
}

// Round 5
// 106.980 us; speedup vs baseline: 1.0093x; 1.0093x over previous
//
#include <hip/hip_runtime.h>
#include <stdint.h>
#include <math.h>

// Negative L1 cdist: out[n,m] = -sum_d |x[n,d] - w[m,d]|
// N=8192, M=1024, D=64, fp32 in/out.
//
// R11 post-mortem: VGPR_Count=48 < 64 needed -> compiler REMATERIALIZED w
// (re-loaded each row-iter). VALU issue 567 cyc/row-iter vs 256 ideal.
// R12 failed to compile: "+v" on float4 array elements = tied INDIRECT
// operands (unsupported). Fix: 64 NAMED SCALAR floats pinned via direct
// "+v" tied operands (supported form), 16 per asm statement.
//   - x: LDS-staged, same-address ds_read_b128 = conflict-free broadcast.
//   - inner loop by construction: v_sub_f32 + v_add_f32(acc,acc,|d|)
//     = 128 full-rate ops/output -> 13.7us VALU-issue floor; expect 16-20us.
//   - (256,4): 128-VGPR budget; usage ~64 w + ~25 misc < 128, no spill.

constexpr int Nn = 8192, Mm = 1024, Dd = 64;
constexpr int NR = 16;                        // n-rows per block

__global__ __launch_bounds__(256, 4) void cdist_l1_f32_kernel(
    const float* __restrict__ x, const float* __restrict__ w,
    float* __restrict__ out)
{
    __shared__ float4 sx[NR * 16];            // 16 rows x 256 B = 4 KB
    const int t   = threadIdx.x;
    const int bid = blockIdx.x;
    const int mg  = bid & 3;                  // m-group: 256 columns each
    const int n0  = (bid >> 2) * NR;
    const int m   = mg * 256 + t;

    // per-lane w row: 16 float4 loads -> 64 named scalars (64 VGPRs)
    const float4* wp = (const float4*)(w + (size_t)m * Dd);
#define LD(i, a, b, c, d) \
    const float4 q##i = wp[i]; \
    float a = q##i.x, b = q##i.y, c = q##i.z, d = q##i.w;
    LD(0,  w00, w01, w02, w03)  LD(1,  w04, w05, w06, w07)
    LD(2,  w08, w09, w10, w11)  LD(3,  w12, w13, w14, w15)
    LD(4,  w16, w17, w18, w19)  LD(5,  w20, w21, w22, w23)
    LD(6,  w24, w25, w26, w27)  LD(7,  w28, w29, w30, w31)
    LD(8,  w32, w33, w34, w35)  LD(9,  w36, w37, w38, w39)
    LD(10, w40, w41, w42, w43)  LD(11, w44, w45, w46, w47)
    LD(12, w48, w49, w50, w51)  LD(13, w52, w53, w54, w55)
    LD(14, w56, w57, w58, w59)  LD(15, w60, w61, w62, w63)
#undef LD

    // Pin: asm-defined scalars cannot be rematerialized -> stay in VGPRs.
    asm volatile("" : "+v"(w00), "+v"(w01), "+v"(w02), "+v"(w03),
                      "+v"(w04), "+v"(w05), "+v"(w06), "+v"(w07),
                      "+v"(w08), "+v"(w09), "+v"(w10), "+v"(w11),
                      "+v"(w12), "+v"(w13), "+v"(w14), "+v"(w15));
    asm volatile("" : "+v"(w16), "+v"(w17), "+v"(w18), "+v"(w19),
                      "+v"(w20), "+v"(w21), "+v"(w22), "+v"(w23),
                      "+v"(w24), "+v"(w25), "+v"(w26), "+v"(w27),
                      "+v"(w28), "+v"(w29), "+v"(w30), "+v"(w31));
    asm volatile("" : "+v"(w32), "+v"(w33), "+v"(w34), "+v"(w35),
                      "+v"(w36), "+v"(w37), "+v"(w38), "+v"(w39),
                      "+v"(w40), "+v"(w41), "+v"(w42), "+v"(w43),
                      "+v"(w44), "+v"(w45), "+v"(w46), "+v"(w47));
    asm volatile("" : "+v"(w48), "+v"(w49), "+v"(w50), "+v"(w51),
                      "+v"(w52), "+v"(w53), "+v"(w54), "+v"(w55),
                      "+v"(w56), "+v"(w57), "+v"(w58), "+v"(w59),
                      "+v"(w60), "+v"(w61), "+v"(w62), "+v"(w63));

    // stage x rows once: 256 threads x 16 B = 4 KB, coalesced
    sx[t] = ((const float4*)(x + (size_t)n0 * Dd))[t];
    __syncthreads();                          // the only barrier

    float* o = out + (size_t)n0 * Mm + m;
#define STEP(i, wa, wb, wc, wd) { \
        const float4 xv = sx[r * 16 + (i)];   /* ds_read_b128 broadcast */ \
        a0 += __builtin_fabsf(xv.x - (wa)); \
        a1 += __builtin_fabsf(xv.y - (wb)); \
        a2 += __builtin_fabsf(xv.z - (wc)); \
        a3 += __builtin_fabsf(xv.w - (wd)); }

#pragma unroll 1
    for (int r = 0; r < NR; ++r) {
        // 4 independent acc chains; body = sub + add(|.|) only
        float a0 = 0.f, a1 = 0.f, a2 = 0.f, a3 = 0.f;
        STEP(0,  w00, w01, w02, w03)  STEP(1,  w04, w05, w06, w07)
        STEP(2,  w08, w09, w10, w11)  STEP(3,  w12, w13, w14, w15)
        STEP(4,  w16, w17, w18, w19)  STEP(5,  w20, w21, w22, w23)
        STEP(6,  w24, w25, w26, w27)  STEP(7,  w28, w29, w30, w31)
        STEP(8,  w32, w33, w34, w35)  STEP(9,  w36, w37, w38, w39)
        STEP(10, w40, w41, w42, w43)  STEP(11, w44, w45, w46, w47)
        STEP(12, w48, w49, w50, w51)  STEP(13, w52, w53, w54, w55)
        STEP(14, w56, w57, w58, w59)  STEP(15, w60, w61, w62, w63)
        // coalesced 256 B/wave segments; nontemporal keeps w/x L2-hot
        __builtin_nontemporal_store(-((a0 + a1) + (a2 + a3)),
                                    o + (size_t)r * Mm);
    }
#undef STEP
}

extern "C" void kernel_launch(void* const* d_in, const int* in_sizes, int n_in,
                              void* d_out, int out_size, void* d_ws, size_t ws_size,
                              hipStream_t stream) {
    (void)in_sizes; (void)n_in; (void)out_size; (void)d_ws; (void)ws_size;
    const float* x = (const float*)d_in[0];   // [8192, 64] fp32
    const float* w = (const float*)d_in[1];   // [1024, 64] fp32
    float* out = (float*)d_out;               // [8192, 1024] fp32

    // (8192/16) n-blocks x 4 m-groups = 2048 blocks = 8 blocks/CU
    cdist_l1_f32_kernel<<<dim3((Nn / NR) * 4), dim3(256), 0, stream>>>(
        x, w, out);
}

// Round 6
// 104.562 us; speedup vs baseline: 1.0326x; 1.0231x over previous
//
#include <hip/hip_runtime.h>
#include <stdint.h>
#include <math.h>

// Negative L1 cdist: out[n,m] = -sum_d |x[n,d] - w[m,d]|
// N=8192, M=1024, D=64, fp32 in/out.
//
// R12 post-mortem: pin stopped global remat (FETCH 4.37MB = ideal) but RA
// moved the 64 pinned w values to AGPRs (VGPR_Count=56 < 64 pinned, no
// scratch traffic) -> v_accvgpr_read plumbing: VALU issue 89k cyc/SIMD =
// 5.4 ops/elem vs ideal 2. ALSO: LDS broadcast was a co-bottleneck
// (8192 ds_read_b128/CU x 12cyc = 41us of LDS-port time alone).
// R13: kill both.
//   - x row via uniform loads -> s_load/SGPR (R11-proven scalarization).
//     SGPR is a FREE VALU operand: no LDS, no broadcast port, no VGPR cost.
//   - w in 64 VGPRs; every USE is inline-asm v_sub_f32 (asm operands must
//     be arch VGPRs; 16 uses/row make AGPR-spill weight prohibitive).
//     Asm is sub-only so the scheduler interleaves 4 chains and folds
//     fabsf into v_add_f32 acc,acc,|t|.
//   - inner loop = 2 full-rate ops/elem = 33k cyc/SIMD = 13.7us floor.
// ~85 live VGPRs @ (256,4) 128-reg budget -> slack, no RA pressure games.

constexpr int Nn = 8192, Mm = 1024, Dd = 64;
constexpr int NR = 16;                        // n-rows per block

__global__ __launch_bounds__(256, 4) void cdist_l1_f32_kernel(
    const float* __restrict__ x, const float* __restrict__ w,
    float* __restrict__ out)
{
    const int t   = threadIdx.x;
    const int bid = blockIdx.x;
    const int mg  = bid & 3;                  // m-group: 256 columns each
    const int n0  = (bid >> 2) * NR;
    const int m   = mg * 256 + t;

    // per-lane w row: 16 float4 loads -> 64 named scalars (64 VGPRs)
    const float4* wp = (const float4*)(w + (size_t)m * Dd);
#define LD(i, a, b, c, d) \
    const float4 q##i = wp[i]; \
    float a = q##i.x, b = q##i.y, c = q##i.z, d = q##i.w;
    LD(0,  w00, w01, w02, w03)  LD(1,  w04, w05, w06, w07)
    LD(2,  w08, w09, w10, w11)  LD(3,  w12, w13, w14, w15)
    LD(4,  w16, w17, w18, w19)  LD(5,  w20, w21, w22, w23)
    LD(6,  w24, w25, w26, w27)  LD(7,  w28, w29, w30, w31)
    LD(8,  w32, w33, w34, w35)  LD(9,  w36, w37, w38, w39)
    LD(10, w40, w41, w42, w43)  LD(11, w44, w45, w46, w47)
    LD(12, w48, w49, w50, w51)  LD(13, w52, w53, w54, w55)
    LD(14, w56, w57, w58, w59)  LD(15, w60, w61, w62, w63)
#undef LD

    float* o = out + (size_t)n0 * Mm + m;

    // asm sub: forces w operand into an arch VGPR at every use site;
    // x operand bound to SGPR ("s") -- free scalar src0 of v_sub_f32.
#define AD(acc, tmp, xs, wv) \
    asm("v_sub_f32 %0, %1, %2" : "=v"(tmp) : "s"(xs), "v"(wv)); \
    acc += __builtin_fabsf(tmp);

#define STEP4(k, wa, wb, wc, wd) \
    AD(a0, t0, xr[(k) + 0], wa)  AD(a1, t1, xr[(k) + 1], wb) \
    AD(a2, t2, xr[(k) + 2], wc)  AD(a3, t3, xr[(k) + 3], wd)

#pragma unroll 1
    for (int r = 0; r < NR; ++r) {
        // block-uniform row -> s_load_dwordx16 into SGPRs (R11-proven)
        const float* __restrict__ xr = x + (size_t)(n0 + r) * Dd;
        float a0 = 0.f, a1 = 0.f, a2 = 0.f, a3 = 0.f;
        float t0, t1, t2, t3;
        STEP4(0,  w00, w01, w02, w03)  STEP4(4,  w04, w05, w06, w07)
        STEP4(8,  w08, w09, w10, w11)  STEP4(12, w12, w13, w14, w15)
        STEP4(16, w16, w17, w18, w19)  STEP4(20, w20, w21, w22, w23)
        STEP4(24, w24, w25, w26, w27)  STEP4(28, w28, w29, w30, w31)
        STEP4(32, w32, w33, w34, w35)  STEP4(36, w36, w37, w38, w39)
        STEP4(40, w40, w41, w42, w43)  STEP4(44, w44, w45, w46, w47)
        STEP4(48, w48, w49, w50, w51)  STEP4(52, w52, w53, w54, w55)
        STEP4(56, w56, w57, w58, w59)  STEP4(60, w60, w61, w62, w63)
        // coalesced 256 B/wave segments; nontemporal keeps w/x L2-hot
        __builtin_nontemporal_store(-((a0 + a1) + (a2 + a3)),
                                    o + (size_t)r * Mm);
    }
#undef STEP4
#undef AD
}

extern "C" void kernel_launch(void* const* d_in, const int* in_sizes, int n_in,
                              void* d_out, int out_size, void* d_ws, size_t ws_size,
                              hipStream_t stream) {
    (void)in_sizes; (void)n_in; (void)out_size; (void)d_ws; (void)ws_size;
    const float* x = (const float*)d_in[0];   // [8192, 64] fp32
    const float* w = (const float*)d_in[1];   // [1024, 64] fp32
    float* out = (float*)d_out;               // [8192, 1024] fp32

    // (8192/16) n-blocks x 4 m-groups = 2048 blocks = 8 blocks/CU
    cdist_l1_f32_kernel<<<dim3((Nn / NR) * 4), dim3(256), 0, stream>>>(
        x, w, out);
}

// Round 7
// 99.927 us; speedup vs baseline: 1.0805x; 1.0464x over previous
//
#include <hip/hip_runtime.h>
#include <stdint.h>
#include <math.h>

// Negative L1 cdist: out[n,m] = -sum_d |x[n,d] - w[m,d]|
// N=8192, M=1024, D=64, fp32 in/out.
//
// R13 post-mortem: use-site asm "v" didn't pin w -- scheduler SANK the 16
// w-loads into the row loop (VGPR=40, FETCH doubled 4.37->8.47MB). Fourth
// round lost to the RA on "keep 64 floats/lane live". Conclusion: the
// structure is RA-hostile; remove the requirement instead of fighting.
// R14: D tiled in 4 chunks of 16. Per lane: acc[16] (NR=16 rows) + ONE
// 16-float w-chunk, loaded once per chunk, reused 256x (16 rows x 16 d).
// Max live ~50-70 VGPR -- nothing to sink/remat/AGPR.
//   - x: block-uniform s_load/SGPR broadcast (R11/R13-proven), free VALU
//     operands, no LDS (R12: LDS broadcast = 41us/CU port wall).
//   - body per (chunk,row): 16 v_sub + 16 v_add(acc,acc,|.|) + 4 tree
//     = 36 VALU vs 32 ideal -> floor 13.7us x1.125 ~ 15.4us.
//   - lane<->m keeps stores coalesced (256B/wave segments).

constexpr int Nn = 8192, Mm = 1024, Dd = 64;
constexpr int NR = 16;                        // n-rows per block

__global__ __launch_bounds__(256, 4) void cdist_l1_f32_kernel(
    const float* __restrict__ x, const float* __restrict__ w,
    float* __restrict__ out)
{
    const int t   = threadIdx.x;
    const int bid = blockIdx.x;
    const int mg  = bid & 3;                  // m-group: 256 columns each
    const int n0  = (bid >> 2) * NR;
    const int m   = mg * 256 + t;

    float acc[NR];
#pragma unroll
    for (int j = 0; j < NR; ++j) acc[j] = 0.f;

    const float4* wp = (const float4*)(w + (size_t)m * Dd);
    const float*  xb = x + (size_t)n0 * Dd;

#pragma unroll 1
    for (int dc = 0; dc < 4; ++dc) {
        // lane-private w chunk: 16 floats, loaded once, used 256x
        const float4 w0 = wp[4 * dc + 0];
        const float4 w1 = wp[4 * dc + 1];
        const float4 w2 = wp[4 * dc + 2];
        const float4 w3 = wp[4 * dc + 3];
#pragma unroll
        for (int j = 0; j < NR; ++j) {
            // block-uniform address -> s_load into SGPRs (free VALU src)
            const float4* xr = (const float4*)(xb + j * Dd + dc * 16);
            const float4 x0 = xr[0], x1 = xr[1], x2 = xr[2], x3 = xr[3];
            // 4 independent chains per row; body = sub + add(|.|) only
            float a = 0.f, b = 0.f, c = 0.f, d = 0.f;
            a += __builtin_fabsf(x0.x - w0.x); b += __builtin_fabsf(x0.y - w0.y);
            c += __builtin_fabsf(x0.z - w0.z); d += __builtin_fabsf(x0.w - w0.w);
            a += __builtin_fabsf(x1.x - w1.x); b += __builtin_fabsf(x1.y - w1.y);
            c += __builtin_fabsf(x1.z - w1.z); d += __builtin_fabsf(x1.w - w1.w);
            a += __builtin_fabsf(x2.x - w2.x); b += __builtin_fabsf(x2.y - w2.y);
            c += __builtin_fabsf(x2.z - w2.z); d += __builtin_fabsf(x2.w - w2.w);
            a += __builtin_fabsf(x3.x - w3.x); b += __builtin_fabsf(x3.y - w3.y);
            c += __builtin_fabsf(x3.z - w3.z); d += __builtin_fabsf(x3.w - w3.w);
            acc[j] += (a + b) + (c + d);      // static index (fully unrolled)
        }
    }

    // coalesced 256 B/wave segments; nontemporal: out is never re-read
    float* o = out + (size_t)n0 * Mm + m;
#pragma unroll
    for (int j = 0; j < NR; ++j)
        __builtin_nontemporal_store(-acc[j], o + (size_t)j * Mm);
}

extern "C" void kernel_launch(void* const* d_in, const int* in_sizes, int n_in,
                              void* d_out, int out_size, void* d_ws, size_t ws_size,
                              hipStream_t stream) {
    (void)in_sizes; (void)n_in; (void)out_size; (void)d_ws; (void)ws_size;
    const float* x = (const float*)d_in[0];   // [8192, 64] fp32
    const float* w = (const float*)d_in[1];   // [1024, 64] fp32
    float* out = (float*)d_out;               // [8192, 1024] fp32

    // (8192/16) n-blocks x 4 m-groups = 2048 blocks = 8 blocks/CU
    cdist_l1_f32_kernel<<<dim3((Nn / NR) * 4), dim3(256), 0, stream>>>(
        x, w, out);
}